// Round 3
// baseline (1574.207 us; speedup 1.0000x reference)
//
#include <hip/hip_runtime.h>
#include <hip/hip_bf16.h>
#include <math.h>

#define MDIM 250
#define NDIM 250
#define DTOT 500          // M + N
#define HDIM 512
#define BATCH 1024
#define N_ITER 1000
#define OMEGA_C 1.8f
#define SIGMA_C 0.1f
#define TOL2 2.5e-9f      // (5e-5)^2 per-row ||ds||^2 early-exit threshold

// ---------------------------------------------------------------------------
// Phase A kernels (one-time setup per call)
// ---------------------------------------------------------------------------

// AinvT[m*500 + i] = Aaug_inv[i*250 + m]   (Aaug_inv is 500x250 row-major)
__global__ void transpose_kernel(const float* __restrict__ Ainv, float* __restrict__ AinvT) {
    int o = blockIdx.x * blockDim.x + threadIdx.x;
    if (o >= MDIM * DTOT) return;
    int m = o / DTOT;
    int i = o % DTOT;
    AinvT[o] = Ainv[i * MDIM + m];
}

// At[k*250 + m] = Aaug[m*500 + k]  for k,m < 250  (first 250 cols of Aaug = A)
__global__ void at_kernel(const float* __restrict__ Aaug, float* __restrict__ At) {
    int o = blockIdx.x * blockDim.x + threadIdx.x;
    if (o >= MDIM * MDIM) return;
    int k = o / MDIM;
    int m = o % MDIM;
    At[o] = Aaug[m * DTOT + k];
}

// ---------------------------------------------------------------------------
// Generic row-tiled MLP layer: out[r,h] = act(sum_k x[r,k] W[k,h] + bias[h])
// 4 rows per block, X rows staged in LDS, W prefetched 16 deep.
// TWOIN: x row = concat(Xa row (250), Xb row (250)).
// ---------------------------------------------------------------------------
template<int K, int H1, bool RELU, bool TWOIN>
__global__ __launch_bounds__(256) void mlp_kernel(const float* __restrict__ Xa,
                                                  const float* __restrict__ Xb,
                                                  const float* __restrict__ W,
                                                  const float* __restrict__ bias,
                                                  float* __restrict__ out) {
    __shared__ float xs[4 * K];   // xs[r*K + k]
    const int t = threadIdx.x;
    const int r0 = blockIdx.x * 4;
    const int h = blockIdx.y * 256 + t;

    for (int e = t; e < 4 * K; e += 256) {
        int r = e / K, k = e % K;
        float v;
        if (TWOIN) v = (k < 250) ? Xa[(r0 + r) * 250 + k] : Xb[(r0 + r) * 250 + (k - 250)];
        else       v = Xa[(r0 + r) * K + k];
        xs[e] = v;
    }
    __syncthreads();

    if (h < H1) {
        float a0, a1, a2, a3;
        a0 = a1 = a2 = a3 = bias[h];
        const float* wp = W + h;
        float g0[8], g1[8];
        #pragma unroll
        for (int u = 0; u < 8; ++u) { g0[u] = wp[u * H1]; g1[u] = wp[(8 + u) * H1]; }
        int kk = 0;
        #pragma unroll 1
        for (int blk = 0; blk < K / 16; ++blk, kk += 16) {
            #pragma unroll
            for (int u = 0; u < 8; ++u) {
                float g = g0[u];
                int kn = kk + 16 + u;
                if (kn < K) g0[u] = wp[kn * H1];
                a0 += g * xs[0 * K + kk + u]; a1 += g * xs[1 * K + kk + u];
                a2 += g * xs[2 * K + kk + u]; a3 += g * xs[3 * K + kk + u];
            }
            #pragma unroll
            for (int u = 0; u < 8; ++u) {
                float g = g1[u];
                int kn = kk + 24 + u;
                if (kn < K) g1[u] = wp[kn * H1];
                a0 += g * xs[0 * K + kk + 8 + u]; a1 += g * xs[1 * K + kk + 8 + u];
                a2 += g * xs[2 * K + kk + 8 + u]; a3 += g * xs[3 * K + kk + 8 + u];
            }
        }
        constexpr int TL = K % 16;
        #pragma unroll
        for (int u = 0; u < (TL < 8 ? TL : 8); ++u) {
            float g = g0[u];
            a0 += g * xs[0 * K + kk + u]; a1 += g * xs[1 * K + kk + u];
            a2 += g * xs[2 * K + kk + u]; a3 += g * xs[3 * K + kk + u];
        }
        #pragma unroll
        for (int u = 0; u < (TL > 8 ? TL - 8 : 0); ++u) {
            float g = g1[u];
            a0 += g * xs[0 * K + kk + 8 + u]; a1 += g * xs[1 * K + kk + 8 + u];
            a2 += g * xs[2 * K + kk + 8 + u]; a3 += g * xs[3 * K + kk + 8 + u];
        }
        if (RELU) { a0 = fmaxf(a0, 0.f); a1 = fmaxf(a1, 0.f); a2 = fmaxf(a2, 0.f); a3 = fmaxf(a3, 0.f); }
        out[(r0 + 0) * H1 + h] = a0;
        out[(r0 + 1) * H1 + h] = a1;
        out[(r0 + 2) * H1 + h] = a2;
        out[(r0 + 3) * H1 + h] = a3;
    }
}

// ---------------------------------------------------------------------------
// Phase B: persistent iteration kernel. 256 blocks x 512 threads (8 waves/CU),
// 4 rows/block. Per iteration (factorized, matches reference):
//   w = A*s_x + s_y - bv          (phase 1, K split across the two thread halves)
//   z = s - w @ Aaug_inv^T        (phase 2, 1 column/thread over 500 threads;
//                                  first MC rows of AinvT served from LDS)
//   tp = (2z - s - 2*sigma*y)/(1+2*sigma);  tk = [tp_:250, soc(tp_250:)]
//   s += omega*(tk - z)
// Early exit: relaxed DR (omega<2) => ||ds||_2 monotone nonincreasing, so if
// per-row ||ds|| < 5e-5 the remaining movement over <=1000 iters is <= 0.05.
// Dynamic LDS layout (floats):
//   ainv_lds[MC*500] | s4[2000] | w4a[1000] | w4b[1000] | w4[1000] | zbuf[2000] | dsum[8]
// ---------------------------------------------------------------------------
template<int MC>
__global__ __launch_bounds__(512) void iterate_kernel(const float* __restrict__ At,
                                                      const float* __restrict__ AinvT,
                                                      const float* __restrict__ b,
                                                      const float* __restrict__ y,
                                                      float* __restrict__ out) {
    extern __shared__ __align__(16) float smem[];
    float* ainv_lds = smem;                 // MC*500
    float* s4   = smem + MC * DTOT;         // 2000: s4[col*4 + row]
    float* w4a  = s4 + 2000;                // 1000: partial w, k-half 0
    float* w4b  = w4a + 1000;               // 1000: partial w, k-half 1
    float* w4   = w4b + 1000;               // 1000: combined w4[m*4 + row]
    float* zbuf = w4 + 1000;                // 2000: zbuf[row*500 + col]
    float* dsum = zbuf + 2000;              // 8

    const int t = threadIdx.x;
    const int row0 = blockIdx.x * 4;
    const float inv12 = 1.0f / (1.0f + 2.0f * SIGMA_C);

    const int half = t >> 8;         // 0 or 1 (k-half for phase 1)
    const int tt = t & 255;          // column m for phase 1
    const int k0 = half * 125;

    const int wv_ = t >> 6;          // wave id 0..7
    const int l = t & 63;
    const int rr = wv_ >> 1;         // elementwise row
    const int hh = wv_ & 1;          // elementwise column half

    // per-thread constants in registers
    float bvr[4];
    #pragma unroll
    for (int r = 0; r < 4; ++r)
        bvr[r] = (t < MDIM) ? b[(row0 + r) * MDIM + t] : 0.0f;
    float yv[4];
    #pragma unroll
    for (int m = 0; m < 4; ++m) {
        int j = hh * NDIM + l + 64 * m;
        yv[m] = (j < (hh ? DTOT : NDIM)) ? y[(row0 + rr) * DTOT + j] : 0.0f;
    }

    // stage AinvT rows [0, MC) into LDS; zero s
    for (int e = t; e < MC * (DTOT / 4); e += 512)
        ((float4*)ainv_lds)[e] = ((const float4*)AinvT)[e];
    for (int e = t; e < 2000; e += 512) s4[e] = 0.0f;
    __syncthreads();

    bool last = false;
    for (int it = 0; ; ++it) {
        // ---- phase 1: partial w_m = sum_{k in half} s_k At[k,m] ----
        if (tt < MDIM) {
            const float* ap = At + tt;   // At[k*250 + tt]
            float g0[10], g1[10];
            #pragma unroll
            for (int u = 0; u < 10; ++u) {
                g0[u] = ap[(k0 + u) * MDIM];
                g1[u] = ap[(k0 + 10 + u) * MDIM];
            }
            float4 acc = {0.f, 0.f, 0.f, 0.f};
            int kk = k0;
            #pragma unroll 1
            for (int blk = 0; blk < 6; ++blk, kk += 20) {       // 120 of 125
                #pragma unroll
                for (int u = 0; u < 10; ++u) {
                    float g = g0[u];
                    int kn = kk + 20 + u;
                    if (kn < k0 + 125) g0[u] = ap[kn * MDIM];
                    float4 sk = *(const float4*)(s4 + 4 * (kk + u));
                    acc.x += g * sk.x; acc.y += g * sk.y; acc.z += g * sk.z; acc.w += g * sk.w;
                }
                #pragma unroll
                for (int u = 0; u < 10; ++u) {
                    float g = g1[u];
                    int kn = kk + 30 + u;
                    if (kn < k0 + 125) g1[u] = ap[kn * MDIM];
                    float4 sk = *(const float4*)(s4 + 4 * (kk + 10 + u));
                    acc.x += g * sk.x; acc.y += g * sk.y; acc.z += g * sk.z; acc.w += g * sk.w;
                }
            }
            #pragma unroll
            for (int u = 0; u < 5; ++u) {                        // tail 120..124 from g0
                float g = g0[u];
                float4 sk = *(const float4*)(s4 + 4 * (kk + u));
                acc.x += g * sk.x; acc.y += g * sk.y; acc.z += g * sk.z; acc.w += g * sk.w;
            }
            float* wp = half ? w4b : w4a;
            *(float4*)(wp + 4 * tt) = acc;
        }
        __syncthreads();

        // ---- combine: w = w4a + w4b + s_y - bv ----
        if (t < MDIM) {
            float4 pa = *(const float4*)(w4a + 4 * t);
            float4 pb = *(const float4*)(w4b + 4 * t);
            float4 sv = *(const float4*)(s4 + 4 * (MDIM + t));
            float4 res;
            res.x = pa.x + pb.x + sv.x - bvr[0];
            res.y = pa.y + pb.y + sv.y - bvr[1];
            res.z = pa.z + pb.z + sv.z - bvr[2];
            res.w = pa.w + pb.w + sv.w - bvr[3];
            *(float4*)(w4 + 4 * t) = res;
        }
        __syncthreads();

        // ---- phase 2: z_i = s_i - sum_m w_m AinvT[m,i]  (1 col/thread) ----
        if (t < DTOT) {
            float4 acc = *(const float4*)(s4 + 4 * t);   // acc.{x..w} = s_i rows 0..3
            // LDS-cached rows m < MC
            #pragma unroll 4
            for (int m = 0; m < MC; ++m) {
                float g = ainv_lds[m * DTOT + t];
                float4 wvv = *(const float4*)(w4 + 4 * m);
                acc.x -= g * wvv.x; acc.y -= g * wvv.y; acc.z -= g * wvv.z; acc.w -= g * wvv.w;
            }
            // global rows m = MC..249
            constexpr int T = MDIM - MC;
            const float* gp = AinvT + MC * DTOT + t;
            float g0[10], g1[10];
            #pragma unroll
            for (int u = 0; u < 10; ++u) { g0[u] = gp[u * DTOT]; g1[u] = gp[(10 + u) * DTOT]; }
            int mm = 0;
            #pragma unroll 1
            for (int blk = 0; blk < T / 20; ++blk, mm += 20) {
                #pragma unroll
                for (int u = 0; u < 10; ++u) {
                    float g = g0[u];
                    int mn = mm + 20 + u;
                    if (mn < T) g0[u] = gp[mn * DTOT];
                    float4 wvv = *(const float4*)(w4 + 4 * (MC + mm + u));
                    acc.x -= g * wvv.x; acc.y -= g * wvv.y; acc.z -= g * wvv.z; acc.w -= g * wvv.w;
                }
                #pragma unroll
                for (int u = 0; u < 10; ++u) {
                    float g = g1[u];
                    int mn = mm + 30 + u;
                    if (mn < T) g1[u] = gp[mn * DTOT];
                    float4 wvv = *(const float4*)(w4 + 4 * (MC + mm + 10 + u));
                    acc.x -= g * wvv.x; acc.y -= g * wvv.y; acc.z -= g * wvv.z; acc.w -= g * wvv.w;
                }
            }
            constexpr int TT = T % 20;
            #pragma unroll
            for (int u = 0; u < (TT < 10 ? TT : 10); ++u) {
                float g = g0[u];
                float4 wvv = *(const float4*)(w4 + 4 * (MC + mm + u));
                acc.x -= g * wvv.x; acc.y -= g * wvv.y; acc.z -= g * wvv.z; acc.w -= g * wvv.w;
            }
            #pragma unroll
            for (int u = 0; u < (TT > 10 ? TT - 10 : 0); ++u) {
                float g = g1[u];
                float4 wvv = *(const float4*)(w4 + 4 * (MC + mm + 10 + u));
                acc.x -= g * wvv.x; acc.y -= g * wvv.y; acc.z -= g * wvv.z; acc.w -= g * wvv.w;
            }
            if (last) {
                out[(row0 + 0) * DTOT + t] = acc.x;
                out[(row0 + 1) * DTOT + t] = acc.y;
                out[(row0 + 2) * DTOT + t] = acc.z;
                out[(row0 + 3) * DTOT + t] = acc.w;
            } else {
                zbuf[0 * DTOT + t] = acc.x;
                zbuf[1 * DTOT + t] = acc.y;
                zbuf[2 * DTOT + t] = acc.z;
                zbuf[3 * DTOT + t] = acc.w;
            }
        }
        if (last) return;
        __syncthreads();

        // ---- elementwise DR update: wave (rr,hh) owns row rr, column half hh ----
        {
            float dsq = 0.0f;
            if (hh == 0) {
                #pragma unroll
                for (int m = 0; m < 4; ++m) {
                    int j = l + 64 * m;
                    if (j < NDIM) {
                        float z = zbuf[rr * DTOT + j];
                        float s = s4[j * 4 + rr];
                        float tp = (2.0f * z - s - 2.0f * SIGMA_C * yv[m]) * inv12;
                        float d = OMEGA_C * (tp - z);
                        s4[j * 4 + rr] = s + d;
                        dsq += d * d;
                    }
                }
            } else {
                float tpv[4], zv[4], sv[4];
                float sums = 0.0f, tval_reg = 0.0f;
                #pragma unroll
                for (int m = 0; m < 4; ++m) {
                    int j = NDIM + l + 64 * m;
                    if (j < DTOT) {
                        float z = zbuf[rr * DTOT + j];
                        float s = s4[j * 4 + rr];
                        float tp = (2.0f * z - s - 2.0f * SIGMA_C * yv[m]) * inv12;
                        tpv[m] = tp; zv[m] = z; sv[m] = s;
                        if (j < DTOT - 1) sums += tp * tp;
                        else tval_reg = tp;
                    }
                }
                #pragma unroll
                for (int off = 32; off > 0; off >>= 1) sums += __shfl_xor(sums, off);
                float norm = sqrtf(sums);
                float tval = __shfl(tval_reg, 57);   // lane 57, m=3 holds j=499
                float fac = (tval + norm) * 0.5f / (norm + 1e-12f);
                bool keep = (norm <= tval);
                bool zero = (norm <= -tval);
                #pragma unroll
                for (int m = 0; m < 4; ++m) {
                    int j = NDIM + l + 64 * m;
                    if (j < DTOT) {
                        float tk;
                        if (j < DTOT - 1) tk = keep ? tpv[m] : (zero ? 0.0f : fac * tpv[m]);
                        else              tk = keep ? tpv[m] : (zero ? 0.0f : (tval + norm) * 0.5f);
                        float d = OMEGA_C * (tk - zv[m]);
                        s4[j * 4 + rr] = sv[m] + d;
                        dsq += d * d;
                    }
                }
            }
            #pragma unroll
            for (int off = 32; off > 0; off >>= 1) dsq += __shfl_xor(dsq, off);
            if (l == 0) dsum[wv_] = dsq;
        }
        __syncthreads();

        if (it >= N_ITER - 1 ||
            (dsum[0] + dsum[1] < TOL2 && dsum[2] + dsum[3] < TOL2 &&
             dsum[4] + dsum[5] < TOL2 && dsum[6] + dsum[7] < TOL2))
            last = true;
    }
}

// ---------------------------------------------------------------------------
extern "C" void kernel_launch(void* const* d_in, const int* in_sizes, int n_in,
                              void* d_out, int out_size, void* d_ws, size_t ws_size,
                              hipStream_t stream) {
    const float* b    = (const float*)d_in[0];
    const float* c    = (const float*)d_in[1];
    const float* W1   = (const float*)d_in[2];
    const float* b1   = (const float*)d_in[3];
    const float* W2   = (const float*)d_in[4];
    const float* b2   = (const float*)d_in[5];
    const float* W3   = (const float*)d_in[6];
    const float* b3   = (const float*)d_in[7];
    const float* Aaug = (const float*)d_in[8];
    const float* Ainv = (const float*)d_in[9];
    float* out = (float*)d_out;

    float* ws = (float*)d_ws;
    float* AinvT = ws;                       // 250*500
    float* At    = AinvT + MDIM * DTOT;      // 250*250
    float* x1    = At + MDIM * MDIM;         // 1024*512
    float* x2    = x1 + BATCH * HDIM;        // 1024*512
    float* y     = x2 + BATCH * HDIM;        // 1024*500

    transpose_kernel<<<(MDIM * DTOT + 255) / 256, 256, 0, stream>>>(Ainv, AinvT);
    at_kernel<<<(MDIM * MDIM + 255) / 256, 256, 0, stream>>>(Aaug, At);
    mlp_kernel<DTOT, HDIM, true, true><<<dim3(BATCH / 4, 2), 256, 0, stream>>>(b, c, W1, b1, x1);
    mlp_kernel<HDIM, HDIM, true, false><<<dim3(BATCH / 4, 2), 256, 0, stream>>>(x1, nullptr, W2, b2, x2);
    mlp_kernel<HDIM, DTOT, false, false><<<dim3(BATCH / 4, 2), 256, 0, stream>>>(x2, nullptr, W3, b3, y);

    // iterate: prefer 148 KB dynamic LDS (60 cached AinvT rows); fall back to
    // 52 KB (12 rows) if the attribute call is rejected.
    constexpr int MC_BIG = 60, MC_SMALL = 12;
    size_t sh_big = (size_t)(MC_BIG * DTOT + 7008) * sizeof(float);    // 148032 B
    size_t sh_small = (size_t)(MC_SMALL * DTOT + 7008) * sizeof(float); // 52032 B
    hipError_t e = hipFuncSetAttribute((const void*)iterate_kernel<MC_BIG>,
                                       hipFuncAttributeMaxDynamicSharedMemorySize,
                                       (int)sh_big);
    if (e == hipSuccess) {
        iterate_kernel<MC_BIG><<<256, 512, sh_big, stream>>>(At, AinvT, b, y, out);
    } else {
        iterate_kernel<MC_SMALL><<<256, 512, sh_small, stream>>>(At, AinvT, b, y, out);
    }
}